// Round 8
// baseline (278.939 us; speedup 1.0000x reference)
//
#include <hip/hip_runtime.h>

#define C_IN 128
#define H_DIM 512
#define O_DIM 128
#define CAP   128   // per-node neighbor capacity; deg ~ Bin(640k,1e-4) = 64±8 (8σ)
#define BM    32    // fused-MLP rows per block
#define FILLB 64    // row-partitioned fill blocks (each owns ~N/64 rows)
#define RPB   160   // max rows per fill block (ceil(10000/64)=157, padded)

typedef __attribute__((ext_vector_type(8))) short short8;
typedef __attribute__((ext_vector_type(4))) float f32x4;

__device__ inline unsigned short f2bf(float f) {
    unsigned int u = __float_as_uint(f);
    unsigned int r = (u + 0x7FFF + ((u >> 16) & 1)) >> 16;   // RNE
    return (unsigned short)r;
}
__device__ inline float bf2f(unsigned short s) {
    return __uint_as_float(((unsigned int)s) << 16);
}

// ---------------------------------------------------------------------------
// prep_fill v4: NO GLOBAL ATOMICS, NO MEMSET.
//  blocks [0,FILLB): own rows [bid*rpb, +rpb). Scan the ENTIRE row array
//    (L2-resident, int4 loads); matched edges (~1/64) get slots from an LDS
//    cursor (LDS atomic, ~zero contention). Each bucket/cnt line is written
//    by exactly ONE block -> no cross-XCD line ping-pong (R7: 33MB RMW
//    traffic, 46us). cnt[r] = exact degree, written once.
//  blocks [FILLB, FILLB+256): 192 transpose tiles (1 elem/thread) + all
//    grid-stride x->bf16 convert into compact xb[N][128].
// ---------------------------------------------------------------------------
__global__ __launch_bounds__(1024)
void prep_fill(const float* __restrict__ w1, unsigned short* __restrict__ w1t,
               const float* __restrict__ w2, unsigned short* __restrict__ w2t,
               const float* __restrict__ x, unsigned short* __restrict__ xb,
               const int* __restrict__ ei, int* __restrict__ cnt,
               unsigned short* __restrict__ bucket, int N, int E) {
    __shared__ int cur[RPB];
    __shared__ float tile[32][33];
    const int bid = blockIdx.x;
    const int t = threadIdx.x;

    if (bid < FILLB) {
        const int rpb = (N + FILLB - 1) / FILLB;
        const int r0 = bid * rpb;
        const int r1 = min(N, r0 + rpb);
        for (int r = t; r < rpb; r += 1024) cur[r] = 0;
        __syncthreads();

        const int E4 = E >> 2;
        for (int k4 = t; k4 < E4; k4 += 1024) {
            int4 rr = ((const int4*)ei)[k4];
#pragma unroll
            for (int i = 0; i < 4; i++) {
                int row = (i == 0) ? rr.x : (i == 1) ? rr.y : (i == 2) ? rr.z : rr.w;
                if (row >= r0 && row < r1) {
                    int col = ei[E + k4 * 4 + i];
                    int slot = atomicAdd(&cur[row - r0], 1);
                    if (slot < CAP) bucket[(long)row * CAP + slot] = (unsigned short)col;
                }
            }
        }
        for (int k = E4 * 4 + t; k < E; k += 1024) {   // tail (E%4)
            int row = ei[k];
            if (row >= r0 && row < r1) {
                int col = ei[E + k];
                int slot = atomicAdd(&cur[row - r0], 1);
                if (slot < CAP) bucket[(long)row * CAP + slot] = (unsigned short)col;
            }
        }
        __syncthreads();
        for (int r = r0 + t; r < r1; r += 1024) cnt[r] = cur[r - r0];
    } else {
        const int pb = bid - FILLB;
        if (pb < 192) {
            // ---- 32x32 transpose tile + fp32->bf16 (1024 thr: 1 elem each) ----
            const float* src; unsigned short* dst; int R, Ccols, bx, by;
            if (pb < 128) { src = w1; dst = w1t; R = 2 * C_IN; Ccols = H_DIM; bx = pb & 15; by = pb >> 4; }
            else { int j = pb - 128; src = w2; dst = w2t; R = H_DIM; Ccols = O_DIM; bx = j & 3; by = j >> 2; }
            const int c0 = bx * 32, r0 = by * 32;
            const int tx = t & 31, ty = t >> 5;
            tile[ty][tx] = src[(long)(r0 + ty) * Ccols + c0 + tx];
            __syncthreads();
            dst[(long)(c0 + ty) * R + r0 + tx] = f2bf(tile[tx][ty]);
        }
        // ---- x -> bf16 convert (grid-stride over the 256 prep blocks) ----
        const int XJ = N * C_IN / 4;
        for (int j = pb * 1024 + t; j < XJ; j += 256 * 1024) {
            int n = j >> 5, c4 = j & 31;
            float4 v = ((const float4*)x)[j];
            ushort4 s;
            s.x = f2bf(v.x); s.y = f2bf(v.y); s.z = f2bf(v.z); s.w = f2bf(v.w);
            *(ushort4*)(xb + (long)n * C_IN + c4 * 4) = s;
        }
    }
}

// ---------------------------------------------------------------------------
// gather (R4-proven split form): one wave per dst node, quarter-wave (16
// lanes x 16B short8) per edge row. Bucket row (256B) register-resident;
// neighbor ids via __shfl. Main stage 32 edges/iter = 8 loads in flight.
// Reads compact xb[N][128]; writes meanb[N][128].
// ---------------------------------------------------------------------------
__global__ __launch_bounds__(256)
void gather_kernel(const unsigned short* __restrict__ bucket,
                   const int* __restrict__ cnt,
                   const unsigned short* __restrict__ xb,
                   unsigned short* __restrict__ meanb, int N) {
    const int lane = threadIdx.x & 63;
    const int n = blockIdx.x * 4 + (threadIdx.x >> 6);
    if (n >= N) return;
    const int g = lane >> 4;          // quarter id 0..3
    const int l16 = lane & 15;
    const int degt = cnt[n];
    const int deg = min(degt, CAP);

    const unsigned int bb = ((const unsigned int*)bucket)[(long)n * (CAP / 2) + lane];

    float acc[8] = {};
    int e = 0;
    for (; e + 32 <= deg; e += 32) {
        int c[8];
#pragma unroll
        for (int i = 0; i < 8; i++) {
            int k = e + 4 * i + g;
            c[i] = (__shfl(bb, k >> 1) >> ((k & 1) << 4)) & 0xffff;
        }
        short8 u[8];
#pragma unroll
        for (int i = 0; i < 8; i++)
            u[i] = *(const short8*)(xb + (long)c[i] * C_IN + l16 * 8);
#pragma unroll
        for (int j = 0; j < 8; j++) {
            float s0 = bf2f((unsigned short)u[0][j]) + bf2f((unsigned short)u[1][j]);
            float s1 = bf2f((unsigned short)u[2][j]) + bf2f((unsigned short)u[3][j]);
            float s2 = bf2f((unsigned short)u[4][j]) + bf2f((unsigned short)u[5][j]);
            float s3 = bf2f((unsigned short)u[6][j]) + bf2f((unsigned short)u[7][j]);
            acc[j] += (s0 + s1) + (s2 + s3);
        }
    }
    if (e + 16 <= deg) {
        int k0 = e + g, k1 = e + 4 + g, k2 = e + 8 + g, k3 = e + 12 + g;
        int c0 = (__shfl(bb, k0 >> 1) >> ((k0 & 1) << 4)) & 0xffff;
        int c1 = (__shfl(bb, k1 >> 1) >> ((k1 & 1) << 4)) & 0xffff;
        int c2 = (__shfl(bb, k2 >> 1) >> ((k2 & 1) << 4)) & 0xffff;
        int c3 = (__shfl(bb, k3 >> 1) >> ((k3 & 1) << 4)) & 0xffff;
        short8 u0 = *(const short8*)(xb + (long)c0 * C_IN + l16 * 8);
        short8 u1 = *(const short8*)(xb + (long)c1 * C_IN + l16 * 8);
        short8 u2 = *(const short8*)(xb + (long)c2 * C_IN + l16 * 8);
        short8 u3 = *(const short8*)(xb + (long)c3 * C_IN + l16 * 8);
#pragma unroll
        for (int j = 0; j < 8; j++)
            acc[j] += (bf2f((unsigned short)u0[j]) + bf2f((unsigned short)u1[j]))
                    + (bf2f((unsigned short)u2[j]) + bf2f((unsigned short)u3[j]));
        e += 16;
    }
    if (e + 8 <= deg) {
        int k0 = e + g, k1 = e + 4 + g;
        int c0 = (__shfl(bb, k0 >> 1) >> ((k0 & 1) << 4)) & 0xffff;
        int c1 = (__shfl(bb, k1 >> 1) >> ((k1 & 1) << 4)) & 0xffff;
        short8 u0 = *(const short8*)(xb + (long)c0 * C_IN + l16 * 8);
        short8 u1 = *(const short8*)(xb + (long)c1 * C_IN + l16 * 8);
#pragma unroll
        for (int j = 0; j < 8; j++)
            acc[j] += bf2f((unsigned short)u0[j]) + bf2f((unsigned short)u1[j]);
        e += 8;
    }
    if (e + 4 <= deg) {
        int k = e + g;
        int c = (__shfl(bb, k >> 1) >> ((k & 1) << 4)) & 0xffff;
        short8 u = *(const short8*)(xb + (long)c * C_IN + l16 * 8);
#pragma unroll
        for (int j = 0; j < 8; j++) acc[j] += bf2f((unsigned short)u[j]);
        e += 4;
    }
    {
        int rem = deg - e;            // 0..3
        int k = e + g;
        unsigned int bv = __shfl(bb, k >> 1);   // shfl before divergence
        if (g < rem) {
            int c = (bv >> ((k & 1) << 4)) & 0xffff;
            short8 u = *(const short8*)(xb + (long)c * C_IN + l16 * 8);
#pragma unroll
            for (int j = 0; j < 8; j++) acc[j] += bf2f((unsigned short)u[j]);
        }
    }
#pragma unroll
    for (int j = 0; j < 8; j++) {
        acc[j] += __shfl_xor(acc[j], 16, 64);
        acc[j] += __shfl_xor(acc[j], 32, 64);
    }
    if (lane < 16) {
        float inv = 1.0f / fmaxf((float)degt, 1.0f);
        short8 mv;
#pragma unroll
        for (int j = 0; j < 8; j++) mv[j] = (short)f2bf(acc[j] * inv);
        *(short8*)(meanb + (long)n * C_IN + l16 * 8) = mv;
    }
}

// ---------------------------------------------------------------------------
// fused MLP (R4-proven form): out[32 rows] = relu(A @ w1t^T + b1) @ w2t^T + b2
// A = [xb row | meanb row]. BM=32, 313 blocks, 256 thr. Phase 1 barrier-free
// (wave w owns h1 cols [w*128,+128)); ONE barrier; phase 2 from LDS h1.
// ---------------------------------------------------------------------------
__global__ __launch_bounds__(256)
void fused_mlp(const unsigned short* __restrict__ xb,     // [N][128] bf16
               const unsigned short* __restrict__ meanb,  // [N][128] bf16
               const unsigned short* __restrict__ w1t,    // [512][256] bf16
               const float* __restrict__ bias1,
               const unsigned short* __restrict__ w2t,    // [128][512] bf16
               const float* __restrict__ bias2,
               float* __restrict__ out, int M) {
    __shared__ __align__(16) unsigned short h1s[BM][520];

    const int t = threadIdx.x;
    const int m0 = blockIdx.x * BM;
    const int lane = t & 63;
    const int w = t >> 6;
    const int l16 = lane & 15;
    const int q = lane >> 4;        // 0..3
    const int q8 = q * 8;

    // A-fragments: k<128 from xb, k>=128 from meanb
    short8 a_reg[2][8];
#pragma unroll
    for (int mf = 0; mf < 2; mf++) {
        int gm = m0 + mf * 16 + l16;
        if (gm < M) {
            const unsigned short* ap = xb + (long)gm * C_IN + q8;
            const unsigned short* mp = meanb + (long)gm * C_IN + q8;
#pragma unroll
            for (int s = 0; s < 4; s++) {
                a_reg[mf][s]     = *(const short8*)(ap + s * 32);
                a_reg[mf][4 + s] = *(const short8*)(mp + s * 32);
            }
        } else {
#pragma unroll
            for (int s = 0; s < 8; s++) a_reg[mf][s] = short8{};
        }
    }

    // phase 1: wave w -> h1 cols [w*128, w*128+128), 4 chunks of 32
#pragma unroll
    for (int nc = 0; nc < 4; nc++) {
        const int colbase = w * 128 + nc * 32;
        f32x4 acc[2][2] = {};
#pragma unroll
        for (int s = 0; s < 8; s++) {
            short8 b0 = *(const short8*)(w1t + (long)(colbase + l16) * 256 + s * 32 + q8);
            short8 b1 = *(const short8*)(w1t + (long)(colbase + 16 + l16) * 256 + s * 32 + q8);
            acc[0][0] = __builtin_amdgcn_mfma_f32_16x16x32_bf16(a_reg[0][s], b0, acc[0][0], 0, 0, 0);
            acc[0][1] = __builtin_amdgcn_mfma_f32_16x16x32_bf16(a_reg[0][s], b1, acc[0][1], 0, 0, 0);
            acc[1][0] = __builtin_amdgcn_mfma_f32_16x16x32_bf16(a_reg[1][s], b0, acc[1][0], 0, 0, 0);
            acc[1][1] = __builtin_amdgcn_mfma_f32_16x16x32_bf16(a_reg[1][s], b1, acc[1][1], 0, 0, 0);
        }
        float bb0 = bias1[colbase + l16];
        float bb1 = bias1[colbase + 16 + l16];
#pragma unroll
        for (int mf = 0; mf < 2; mf++) {
#pragma unroll
            for (int r = 0; r < 4; r++) {
                int m = mf * 16 + q * 4 + r;
                h1s[m][colbase + l16]      = f2bf(fmaxf(acc[mf][0][r] + bb0, 0.f));
                h1s[m][colbase + 16 + l16] = f2bf(fmaxf(acc[mf][1][r] + bb1, 0.f));
            }
        }
    }
    __syncthreads();

    // phase 2: wave w -> out cols [w*32, w*32+32), 32 rows, K=512
    f32x4 acc2[2][2] = {};
    const int wn = w * 32;
#pragma unroll
    for (int ks = 0; ks < 16; ks++) {
        short8 a0 = *(const short8*)&h1s[l16][ks * 32 + q8];
        short8 a1 = *(const short8*)&h1s[16 + l16][ks * 32 + q8];
        short8 b0 = *(const short8*)(w2t + (long)(wn + l16) * H_DIM + ks * 32 + q8);
        short8 b1 = *(const short8*)(w2t + (long)(wn + 16 + l16) * H_DIM + ks * 32 + q8);
        acc2[0][0] = __builtin_amdgcn_mfma_f32_16x16x32_bf16(a0, b0, acc2[0][0], 0, 0, 0);
        acc2[0][1] = __builtin_amdgcn_mfma_f32_16x16x32_bf16(a0, b1, acc2[0][1], 0, 0, 0);
        acc2[1][0] = __builtin_amdgcn_mfma_f32_16x16x32_bf16(a1, b0, acc2[1][0], 0, 0, 0);
        acc2[1][1] = __builtin_amdgcn_mfma_f32_16x16x32_bf16(a1, b1, acc2[1][1], 0, 0, 0);
    }
#pragma unroll
    for (int mf = 0; mf < 2; mf++) {
#pragma unroll
        for (int nf = 0; nf < 2; nf++) {
            int gn = wn + nf * 16 + l16;
            float bb = bias2[gn];
#pragma unroll
            for (int r = 0; r < 4; r++) {
                int gm = m0 + mf * 16 + q * 4 + r;
                if (gm < M) out[(long)gm * O_DIM + gn] = acc2[mf][nf][r] + bb;
            }
        }
    }
}

extern "C" void kernel_launch(void* const* d_in, const int* in_sizes, int n_in,
                              void* d_out, int out_size, void* d_ws, size_t ws_size,
                              hipStream_t stream) {
    const float* x  = (const float*)d_in[0];   // [N, C]
    const int*   ei = (const int*)d_in[1];     // [2, E]
    const float* w1 = (const float*)d_in[2];   // [2C, H]
    const float* b1 = (const float*)d_in[3];   // [H]
    const float* w2 = (const float*)d_in[4];   // [H, O]
    const float* b2 = (const float*)d_in[5];   // [O]
    float* out = (float*)d_out;                // [N, O]

    const int N = in_sizes[0] / C_IN;
    const int E = in_sizes[1] / 2;

    // ws layout: xb [N][128] | meanb [N][128] | w1t [512][256] | w2t [128][512]
    //            | cnt [N] int | bucket [N*CAP] ushort
    unsigned short* xb = (unsigned short*)d_ws;
    unsigned short* meanb = xb + (size_t)N * C_IN;
    unsigned short* w1t = meanb + (size_t)N * C_IN;
    unsigned short* w2t = w1t + (size_t)H_DIM * (2 * C_IN);
    int* cnt = (int*)(w2t + (size_t)O_DIM * H_DIM);
    unsigned short* bucket = (unsigned short*)(cnt + (size_t)N);

    // no memset: cnt fully written by prep_fill; bucket slots beyond deg unread
    prep_fill<<<FILLB + 256, 1024, 0, stream>>>(w1, w1t, w2, w2t, x, xb, ei, cnt, bucket, N, E);
    gather_kernel<<<(N + 3) / 4, 256, 0, stream>>>(bucket, cnt, xb, meanb, N);
    fused_mlp<<<(N + BM - 1) / BM, 256, 0, stream>>>(xb, meanb, w1t, b1, w2t, b2, out, N);
}

// Round 9
// 153.895 us; speedup vs baseline: 1.8125x; 1.8125x over previous
//
#include <hip/hip_runtime.h>

#define C_IN 128
#define H_DIM 512
#define O_DIM 128
#define CAP   128   // per-node neighbor capacity; deg ~ Bin(640k,1e-4) = 64±8 (8σ)
#define BM    32    // fused-MLP rows per block

typedef __attribute__((ext_vector_type(8))) short short8;
typedef __attribute__((ext_vector_type(4))) float f32x4;

__device__ inline unsigned short f2bf(float f) {
    unsigned int u = __float_as_uint(f);
    unsigned int r = (u + 0x7FFF + ((u >> 16) & 1)) >> 16;   // RNE
    return (unsigned short)r;
}
__device__ inline float bf2f(unsigned short s) {
    return __uint_as_float(((unsigned int)s) << 16);
}

// ---------------------------------------------------------------------------
// 32x32 transpose tile + fp32->bf16: dst[c][r] = bf16(src[r][c])
// ---------------------------------------------------------------------------
__device__ inline void tr_tile(const float* __restrict__ src, unsigned short* __restrict__ dst,
                               int R, int Ccols, int bx, int by) {
    __shared__ float tile[32][33];
    const int c0 = bx * 32, r0 = by * 32;
    const int tx = threadIdx.x & 31, ty = threadIdx.x >> 5;   // 32 x 8
#pragma unroll
    for (int i = 0; i < 32; i += 8)
        tile[ty + i][tx] = src[(long)(r0 + ty + i) * Ccols + c0 + tx];
    __syncthreads();
#pragma unroll
    for (int i = 0; i < 32; i += 8)
        dst[(long)(c0 + ty + i) * R + r0 + tx] = f2bf(tile[tx][ty + i]);
}

// ---------------------------------------------------------------------------
// prep_fill (R4-proven form; fill ledger: global atomics 45us BEAT LDS-claim
// 72-84us, counting-sort, and row-scan 174us). Convert jobs first (R4 order).
// Writes COMPACT xb[N][128] (2.5MB -> fits each XCD's 4MB L2 for gather).
// bucket stores are NON-TEMPORAL: write-once data, keep L2 clean for xb.
// ---------------------------------------------------------------------------
__global__ __launch_bounds__(256)
void prep_fill(const float* __restrict__ w1, unsigned short* __restrict__ w1t,
               const float* __restrict__ w2, unsigned short* __restrict__ w2t,
               const float* __restrict__ x, unsigned short* __restrict__ xb,
               const int* __restrict__ ei, int* __restrict__ cnt,
               unsigned short* __restrict__ bucket, int N, int E) {
    const int bid = blockIdx.x;
    if (bid < 192) {
        if (bid < 128) tr_tile(w1, w1t, 2 * C_IN, H_DIM, bid & 15, bid >> 4);
        else { int j = bid - 128; tr_tile(w2, w2t, H_DIM, O_DIM, j & 3, j >> 2); }
    }

    const int XJ = N * C_IN / 4;          // float4 convert jobs (first: R4 order)
    const int FJ = (E + 3) / 4;           // 4-edge fill jobs
    const int gtid = bid * 256 + threadIdx.x;
    const int nthr = gridDim.x * 256;
    const bool al = ((E & 3) == 0);
    for (int j = gtid; j < XJ + FJ; j += nthr) {
        if (j < XJ) {
            int n = j >> 5, c4 = j & 31;
            float4 v = ((const float4*)x)[j];
            ushort4 s;
            s.x = f2bf(v.x); s.y = f2bf(v.y); s.z = f2bf(v.z); s.w = f2bf(v.w);
            *(ushort4*)(xb + (long)n * C_IN + c4 * 4) = s;
        } else {
            int e = (j - XJ) * 4;
            if (al) {
                int4 r = *(const int4*)(ei + e);
                int4 c = *(const int4*)(ei + E + e);
                int s0 = atomicAdd(&cnt[r.x], 1);
                int s1 = atomicAdd(&cnt[r.y], 1);
                int s2 = atomicAdd(&cnt[r.z], 1);
                int s3 = atomicAdd(&cnt[r.w], 1);
                if (s0 < CAP) __builtin_nontemporal_store((unsigned short)c.x, &bucket[(long)r.x * CAP + s0]);
                if (s1 < CAP) __builtin_nontemporal_store((unsigned short)c.y, &bucket[(long)r.y * CAP + s1]);
                if (s2 < CAP) __builtin_nontemporal_store((unsigned short)c.z, &bucket[(long)r.z * CAP + s2]);
                if (s3 < CAP) __builtin_nontemporal_store((unsigned short)c.w, &bucket[(long)r.w * CAP + s3]);
            } else {
                for (int k = e; k < E && k < e + 4; k++) {
                    int row = ei[k];
                    int col = ei[E + k];
                    int slot = atomicAdd(&cnt[row], 1);
                    if (slot < CAP) __builtin_nontemporal_store((unsigned short)col, &bucket[(long)row * CAP + slot]);
                }
            }
        }
    }
}

// ---------------------------------------------------------------------------
// gather (R4-proven split form, 2500 blocks TLP): one wave per dst node,
// quarter-wave (16 lanes x 16B short8) per edge row. Bucket row (256B)
// register-resident via ONE NT uint load/lane; neighbor ids via __shfl.
// Main stage 32 edges/iter = 8 loads in flight. xb reads L2-CACHED (2.5MB
// resident per XCD); bucket NT-load + meanb NT-store keep L2 clean for xb.
// ---------------------------------------------------------------------------
__global__ __launch_bounds__(256)
void gather_kernel(const unsigned short* __restrict__ bucket,
                   const int* __restrict__ cnt,
                   const unsigned short* __restrict__ xb,
                   unsigned short* __restrict__ meanb, int N) {
    const int lane = threadIdx.x & 63;
    const int n = blockIdx.x * 4 + (threadIdx.x >> 6);
    if (n >= N) return;
    const int g = lane >> 4;          // quarter id 0..3
    const int l16 = lane & 15;
    const int degt = cnt[n];
    const int deg = min(degt, CAP);

    const unsigned int bb =
        __builtin_nontemporal_load(&((const unsigned int*)bucket)[(long)n * (CAP / 2) + lane]);

    float acc[8] = {};
    int e = 0;
    for (; e + 32 <= deg; e += 32) {
        int c[8];
#pragma unroll
        for (int i = 0; i < 8; i++) {
            int k = e + 4 * i + g;
            c[i] = (__shfl(bb, k >> 1) >> ((k & 1) << 4)) & 0xffff;
        }
        short8 u[8];
#pragma unroll
        for (int i = 0; i < 8; i++)
            u[i] = *(const short8*)(xb + (long)c[i] * C_IN + l16 * 8);
#pragma unroll
        for (int j = 0; j < 8; j++) {
            float s0 = bf2f((unsigned short)u[0][j]) + bf2f((unsigned short)u[1][j]);
            float s1 = bf2f((unsigned short)u[2][j]) + bf2f((unsigned short)u[3][j]);
            float s2 = bf2f((unsigned short)u[4][j]) + bf2f((unsigned short)u[5][j]);
            float s3 = bf2f((unsigned short)u[6][j]) + bf2f((unsigned short)u[7][j]);
            acc[j] += (s0 + s1) + (s2 + s3);
        }
    }
    if (e + 16 <= deg) {
        int k0 = e + g, k1 = e + 4 + g, k2 = e + 8 + g, k3 = e + 12 + g;
        int c0 = (__shfl(bb, k0 >> 1) >> ((k0 & 1) << 4)) & 0xffff;
        int c1 = (__shfl(bb, k1 >> 1) >> ((k1 & 1) << 4)) & 0xffff;
        int c2 = (__shfl(bb, k2 >> 1) >> ((k2 & 1) << 4)) & 0xffff;
        int c3 = (__shfl(bb, k3 >> 1) >> ((k3 & 1) << 4)) & 0xffff;
        short8 u0 = *(const short8*)(xb + (long)c0 * C_IN + l16 * 8);
        short8 u1 = *(const short8*)(xb + (long)c1 * C_IN + l16 * 8);
        short8 u2 = *(const short8*)(xb + (long)c2 * C_IN + l16 * 8);
        short8 u3 = *(const short8*)(xb + (long)c3 * C_IN + l16 * 8);
#pragma unroll
        for (int j = 0; j < 8; j++)
            acc[j] += (bf2f((unsigned short)u0[j]) + bf2f((unsigned short)u1[j]))
                    + (bf2f((unsigned short)u2[j]) + bf2f((unsigned short)u3[j]));
        e += 16;
    }
    if (e + 8 <= deg) {
        int k0 = e + g, k1 = e + 4 + g;
        int c0 = (__shfl(bb, k0 >> 1) >> ((k0 & 1) << 4)) & 0xffff;
        int c1 = (__shfl(bb, k1 >> 1) >> ((k1 & 1) << 4)) & 0xffff;
        short8 u0 = *(const short8*)(xb + (long)c0 * C_IN + l16 * 8);
        short8 u1 = *(const short8*)(xb + (long)c1 * C_IN + l16 * 8);
#pragma unroll
        for (int j = 0; j < 8; j++)
            acc[j] += bf2f((unsigned short)u0[j]) + bf2f((unsigned short)u1[j]);
        e += 8;
    }
    if (e + 4 <= deg) {
        int k = e + g;
        int c = (__shfl(bb, k >> 1) >> ((k & 1) << 4)) & 0xffff;
        short8 u = *(const short8*)(xb + (long)c * C_IN + l16 * 8);
#pragma unroll
        for (int j = 0; j < 8; j++) acc[j] += bf2f((unsigned short)u[j]);
        e += 4;
    }
    {
        int rem = deg - e;            // 0..3
        int k = e + g;
        unsigned int bv = __shfl(bb, k >> 1);   // shfl before divergence
        if (g < rem) {
            int c = (bv >> ((k & 1) << 4)) & 0xffff;
            short8 u = *(const short8*)(xb + (long)c * C_IN + l16 * 8);
#pragma unroll
            for (int j = 0; j < 8; j++) acc[j] += bf2f((unsigned short)u[j]);
        }
    }
#pragma unroll
    for (int j = 0; j < 8; j++) {
        acc[j] += __shfl_xor(acc[j], 16, 64);
        acc[j] += __shfl_xor(acc[j], 32, 64);
    }
    if (lane < 16) {
        float inv = 1.0f / fmaxf((float)degt, 1.0f);
        short8 mv;
#pragma unroll
        for (int j = 0; j < 8; j++) mv[j] = (short)f2bf(acc[j] * inv);
        __builtin_nontemporal_store(mv, (short8*)(meanb + (long)n * C_IN + l16 * 8));
    }
}

// ---------------------------------------------------------------------------
// fused MLP (R4/R8-proven form): out[32 rows] = relu(A@w1t^T+b1)@w2t^T+b2,
// A = [xb row | meanb row]. BM=32, 313 blocks, 256 thr. Phase 1 barrier-free
// (wave w owns h1 cols [w*128,+128)); ONE barrier; phase 2 from LDS h1.
// out stores NT (write-once).
// ---------------------------------------------------------------------------
__global__ __launch_bounds__(256)
void fused_mlp(const unsigned short* __restrict__ xb,     // [N][128] bf16
               const unsigned short* __restrict__ meanb,  // [N][128] bf16
               const unsigned short* __restrict__ w1t,    // [512][256] bf16
               const float* __restrict__ bias1,
               const unsigned short* __restrict__ w2t,    // [128][512] bf16
               const float* __restrict__ bias2,
               float* __restrict__ out, int M) {
    __shared__ __align__(16) unsigned short h1s[BM][520];

    const int t = threadIdx.x;
    const int m0 = blockIdx.x * BM;
    const int lane = t & 63;
    const int w = t >> 6;
    const int l16 = lane & 15;
    const int q = lane >> 4;        // 0..3
    const int q8 = q * 8;

    // A-fragments: k<128 from xb, k>=128 from meanb
    short8 a_reg[2][8];
#pragma unroll
    for (int mf = 0; mf < 2; mf++) {
        int gm = m0 + mf * 16 + l16;
        if (gm < M) {
            const unsigned short* ap = xb + (long)gm * C_IN + q8;
            const unsigned short* mp = meanb + (long)gm * C_IN + q8;
#pragma unroll
            for (int s = 0; s < 4; s++) {
                a_reg[mf][s]     = *(const short8*)(ap + s * 32);
                a_reg[mf][4 + s] = *(const short8*)(mp + s * 32);
            }
        } else {
#pragma unroll
            for (int s = 0; s < 8; s++) a_reg[mf][s] = short8{};
        }
    }

    // phase 1: wave w -> h1 cols [w*128, w*128+128), 4 chunks of 32
#pragma unroll
    for (int nc = 0; nc < 4; nc++) {
        const int colbase = w * 128 + nc * 32;
        f32x4 acc[2][2] = {};
#pragma unroll
        for (int s = 0; s < 8; s++) {
            short8 b0 = *(const short8*)(w1t + (long)(colbase + l16) * 256 + s * 32 + q8);
            short8 b1 = *(const short8*)(w1t + (long)(colbase + 16 + l16) * 256 + s * 32 + q8);
            acc[0][0] = __builtin_amdgcn_mfma_f32_16x16x32_bf16(a_reg[0][s], b0, acc[0][0], 0, 0, 0);
            acc[0][1] = __builtin_amdgcn_mfma_f32_16x16x32_bf16(a_reg[0][s], b1, acc[0][1], 0, 0, 0);
            acc[1][0] = __builtin_amdgcn_mfma_f32_16x16x32_bf16(a_reg[1][s], b0, acc[1][0], 0, 0, 0);
            acc[1][1] = __builtin_amdgcn_mfma_f32_16x16x32_bf16(a_reg[1][s], b1, acc[1][1], 0, 0, 0);
        }
        float bb0 = bias1[colbase + l16];
        float bb1 = bias1[colbase + 16 + l16];
#pragma unroll
        for (int mf = 0; mf < 2; mf++) {
#pragma unroll
            for (int r = 0; r < 4; r++) {
                int m = mf * 16 + q * 4 + r;
                h1s[m][colbase + l16]      = f2bf(fmaxf(acc[mf][0][r] + bb0, 0.f));
                h1s[m][colbase + 16 + l16] = f2bf(fmaxf(acc[mf][1][r] + bb1, 0.f));
            }
        }
    }
    __syncthreads();

    // phase 2: wave w -> out cols [w*32, w*32+32), 32 rows, K=512
    f32x4 acc2[2][2] = {};
    const int wn = w * 32;
#pragma unroll
    for (int ks = 0; ks < 16; ks++) {
        short8 a0 = *(const short8*)&h1s[l16][ks * 32 + q8];
        short8 a1 = *(const short8*)&h1s[16 + l16][ks * 32 + q8];
        short8 b0 = *(const short8*)(w2t + (long)(wn + l16) * H_DIM + ks * 32 + q8);
        short8 b1 = *(const short8*)(w2t + (long)(wn + 16 + l16) * H_DIM + ks * 32 + q8);
        acc2[0][0] = __builtin_amdgcn_mfma_f32_16x16x32_bf16(a0, b0, acc2[0][0], 0, 0, 0);
        acc2[0][1] = __builtin_amdgcn_mfma_f32_16x16x32_bf16(a0, b1, acc2[0][1], 0, 0, 0);
        acc2[1][0] = __builtin_amdgcn_mfma_f32_16x16x32_bf16(a1, b0, acc2[1][0], 0, 0, 0);
        acc2[1][1] = __builtin_amdgcn_mfma_f32_16x16x32_bf16(a1, b1, acc2[1][1], 0, 0, 0);
    }
#pragma unroll
    for (int mf = 0; mf < 2; mf++) {
#pragma unroll
        for (int nf = 0; nf < 2; nf++) {
            int gn = wn + nf * 16 + l16;
            float bb = bias2[gn];
#pragma unroll
            for (int r = 0; r < 4; r++) {
                int gm = m0 + mf * 16 + q * 4 + r;
                if (gm < M) __builtin_nontemporal_store(acc2[mf][nf][r] + bb, &out[(long)gm * O_DIM + gn]);
            }
        }
    }
}

extern "C" void kernel_launch(void* const* d_in, const int* in_sizes, int n_in,
                              void* d_out, int out_size, void* d_ws, size_t ws_size,
                              hipStream_t stream) {
    const float* x  = (const float*)d_in[0];   // [N, C]
    const int*   ei = (const int*)d_in[1];     // [2, E]
    const float* w1 = (const float*)d_in[2];   // [2C, H]
    const float* b1 = (const float*)d_in[3];   // [H]
    const float* w2 = (const float*)d_in[4];   // [H, O]
    const float* b2 = (const float*)d_in[5];   // [O]
    float* out = (float*)d_out;                // [N, O]

    const int N = in_sizes[0] / C_IN;
    const int E = in_sizes[1] / 2;

    // ws layout: xb [N][128] | meanb [N][128] | w1t [512][256] | w2t [128][512]
    //            | cnt [N] int | bucket [N*CAP] ushort
    unsigned short* xb = (unsigned short*)d_ws;
    unsigned short* meanb = xb + (size_t)N * C_IN;
    unsigned short* w1t = meanb + (size_t)N * C_IN;
    unsigned short* w2t = w1t + (size_t)H_DIM * (2 * C_IN);
    int* cnt = (int*)(w2t + (size_t)O_DIM * H_DIM);
    unsigned short* bucket = (unsigned short*)(cnt + (size_t)N);

    hipMemsetAsync(cnt, 0, (size_t)N * sizeof(int), stream);
    prep_fill<<<1024, 256, 0, stream>>>(w1, w1t, w2, w2t, x, xb, ei, cnt, bucket, N, E);
    gather_kernel<<<(N + 3) / 4, 256, 0, stream>>>(bucket, cnt, xb, meanb, N);
    fused_mlp<<<(N + BM - 1) / BM, 256, 0, stream>>>(xb, meanb, w1t, b1, w2t, b2, out, N);
}

// Round 10
// 138.828 us; speedup vs baseline: 2.0092x; 1.1085x over previous
//
#include <hip/hip_runtime.h>

#define C_IN 128
#define H_DIM 512
#define O_DIM 128
#define CAP   128   // per-node neighbor capacity; deg ~ Bin(640k,1e-4) = 64±8 (8σ)
#define PAD   16    // counter padding: 1 int per 64B line (R9: unpadded cnt ->
                    // 16 counters/line -> ~1024 serialized atomics/line = 43us)
#define BM    32    // fused-MLP rows per block

typedef __attribute__((ext_vector_type(8))) short short8;
typedef __attribute__((ext_vector_type(4))) float f32x4;

__device__ inline unsigned short f2bf(float f) {
    unsigned int u = __float_as_uint(f);
    unsigned int r = (u + 0x7FFF + ((u >> 16) & 1)) >> 16;   // RNE
    return (unsigned short)r;
}
__device__ inline float bf2f(unsigned short s) {
    return __uint_as_float(((unsigned int)s) << 16);
}

// ---------------------------------------------------------------------------
// 32x32 transpose tile + fp32->bf16: dst[c][r] = bf16(src[r][c])
// ---------------------------------------------------------------------------
__device__ inline void tr_tile(const float* __restrict__ src, unsigned short* __restrict__ dst,
                               int R, int Ccols, int bx, int by) {
    __shared__ float tile[32][33];
    const int c0 = bx * 32, r0 = by * 32;
    const int tx = threadIdx.x & 31, ty = threadIdx.x >> 5;   // 32 x 8
#pragma unroll
    for (int i = 0; i < 32; i += 8)
        tile[ty + i][tx] = src[(long)(r0 + ty + i) * Ccols + c0 + tx];
    __syncthreads();
#pragma unroll
    for (int i = 0; i < 32; i += 8)
        dst[(long)(c0 + ty + i) * R + r0 + tx] = f2bf(tile[tx][ty + i]);
}

// ---------------------------------------------------------------------------
// prep_fill (R4-proven merged form + PADDED counters, NO NT):
//  blocks 0..191: one 32x32 weight-transpose tile each
//  all blocks: grid-stride over {x->bf16 convert jobs} ++ {4-edge fill jobs}
// Fill ledger: global atomics (45us unpadded) beat LDS-claim (72-84us),
// counting-sort (3-pass, net loss), row-scan (174us). R9 showed the 45us is
// same-LINE atomic serialization -> PAD=16 gives each counter its own line.
// ---------------------------------------------------------------------------
__global__ __launch_bounds__(256)
void prep_fill(const float* __restrict__ w1, unsigned short* __restrict__ w1t,
               const float* __restrict__ w2, unsigned short* __restrict__ w2t,
               const float* __restrict__ x, unsigned short* __restrict__ xb,
               const int* __restrict__ ei, int* __restrict__ cnt_p,
               unsigned short* __restrict__ bucket, int N, int E) {
    const int bid = blockIdx.x;
    if (bid < 192) {
        if (bid < 128) tr_tile(w1, w1t, 2 * C_IN, H_DIM, bid & 15, bid >> 4);
        else { int j = bid - 128; tr_tile(w2, w2t, H_DIM, O_DIM, j & 3, j >> 2); }
    }

    const int XJ = N * C_IN / 4;          // float4 convert jobs (R4 order)
    const int FJ = (E + 3) / 4;           // 4-edge fill jobs
    const int gtid = bid * 256 + threadIdx.x;
    const int nthr = gridDim.x * 256;
    const bool al = ((E & 3) == 0);
    for (int j = gtid; j < XJ + FJ; j += nthr) {
        if (j < XJ) {
            int n = j >> 5, c4 = j & 31;
            float4 v = ((const float4*)x)[j];
            ushort4 s;
            s.x = f2bf(v.x); s.y = f2bf(v.y); s.z = f2bf(v.z); s.w = f2bf(v.w);
            *(ushort4*)(xb + (long)n * C_IN + c4 * 4) = s;
        } else {
            int e = (j - XJ) * 4;
            if (al) {
                int4 r = *(const int4*)(ei + e);
                int4 c = *(const int4*)(ei + E + e);
                int s0 = atomicAdd(&cnt_p[r.x * PAD], 1);
                int s1 = atomicAdd(&cnt_p[r.y * PAD], 1);
                int s2 = atomicAdd(&cnt_p[r.z * PAD], 1);
                int s3 = atomicAdd(&cnt_p[r.w * PAD], 1);
                if (s0 < CAP) bucket[(long)r.x * CAP + s0] = (unsigned short)c.x;
                if (s1 < CAP) bucket[(long)r.y * CAP + s1] = (unsigned short)c.y;
                if (s2 < CAP) bucket[(long)r.z * CAP + s2] = (unsigned short)c.z;
                if (s3 < CAP) bucket[(long)r.w * CAP + s3] = (unsigned short)c.w;
            } else {
                for (int k = e; k < E && k < e + 4; k++) {
                    int row = ei[k];
                    int col = ei[E + k];
                    int slot = atomicAdd(&cnt_p[row * PAD], 1);
                    if (slot < CAP) bucket[(long)row * CAP + slot] = (unsigned short)col;
                }
            }
        }
    }
}

// ---------------------------------------------------------------------------
// gather (R4-proven split form, 2500 blocks TLP, NO NT): one wave per dst
// node, quarter-wave (16 lanes x 16B short8) per edge row. Bucket row (256B)
// register-resident; neighbor ids via __shfl. 32 edges/iter = 8 loads in
// flight. xb is 2.5MB -> L2-resident per XCD (vs R4's 5MB interleaved h0).
// ---------------------------------------------------------------------------
__global__ __launch_bounds__(256)
void gather_kernel(const unsigned short* __restrict__ bucket,
                   const int* __restrict__ cnt_p,
                   const unsigned short* __restrict__ xb,
                   unsigned short* __restrict__ meanb, int N) {
    const int lane = threadIdx.x & 63;
    const int n = blockIdx.x * 4 + (threadIdx.x >> 6);
    if (n >= N) return;
    const int g = lane >> 4;          // quarter id 0..3
    const int l16 = lane & 15;
    const int degt = cnt_p[n * PAD];
    const int deg = min(degt, CAP);

    const unsigned int bb = ((const unsigned int*)bucket)[(long)n * (CAP / 2) + lane];

    float acc[8] = {};
    int e = 0;
    for (; e + 32 <= deg; e += 32) {
        int c[8];
#pragma unroll
        for (int i = 0; i < 8; i++) {
            int k = e + 4 * i + g;
            c[i] = (__shfl(bb, k >> 1) >> ((k & 1) << 4)) & 0xffff;
        }
        short8 u[8];
#pragma unroll
        for (int i = 0; i < 8; i++)
            u[i] = *(const short8*)(xb + (long)c[i] * C_IN + l16 * 8);
#pragma unroll
        for (int j = 0; j < 8; j++) {
            float s0 = bf2f((unsigned short)u[0][j]) + bf2f((unsigned short)u[1][j]);
            float s1 = bf2f((unsigned short)u[2][j]) + bf2f((unsigned short)u[3][j]);
            float s2 = bf2f((unsigned short)u[4][j]) + bf2f((unsigned short)u[5][j]);
            float s3 = bf2f((unsigned short)u[6][j]) + bf2f((unsigned short)u[7][j]);
            acc[j] += (s0 + s1) + (s2 + s3);
        }
    }
    if (e + 16 <= deg) {
        int k0 = e + g, k1 = e + 4 + g, k2 = e + 8 + g, k3 = e + 12 + g;
        int c0 = (__shfl(bb, k0 >> 1) >> ((k0 & 1) << 4)) & 0xffff;
        int c1 = (__shfl(bb, k1 >> 1) >> ((k1 & 1) << 4)) & 0xffff;
        int c2 = (__shfl(bb, k2 >> 1) >> ((k2 & 1) << 4)) & 0xffff;
        int c3 = (__shfl(bb, k3 >> 1) >> ((k3 & 1) << 4)) & 0xffff;
        short8 u0 = *(const short8*)(xb + (long)c0 * C_IN + l16 * 8);
        short8 u1 = *(const short8*)(xb + (long)c1 * C_IN + l16 * 8);
        short8 u2 = *(const short8*)(xb + (long)c2 * C_IN + l16 * 8);
        short8 u3 = *(const short8*)(xb + (long)c3 * C_IN + l16 * 8);
#pragma unroll
        for (int j = 0; j < 8; j++)
            acc[j] += (bf2f((unsigned short)u0[j]) + bf2f((unsigned short)u1[j]))
                    + (bf2f((unsigned short)u2[j]) + bf2f((unsigned short)u3[j]));
        e += 16;
    }
    if (e + 8 <= deg) {
        int k0 = e + g, k1 = e + 4 + g;
        int c0 = (__shfl(bb, k0 >> 1) >> ((k0 & 1) << 4)) & 0xffff;
        int c1 = (__shfl(bb, k1 >> 1) >> ((k1 & 1) << 4)) & 0xffff;
        short8 u0 = *(const short8*)(xb + (long)c0 * C_IN + l16 * 8);
        short8 u1 = *(const short8*)(xb + (long)c1 * C_IN + l16 * 8);
#pragma unroll
        for (int j = 0; j < 8; j++)
            acc[j] += bf2f((unsigned short)u0[j]) + bf2f((unsigned short)u1[j]);
        e += 8;
    }
    if (e + 4 <= deg) {
        int k = e + g;
        int c = (__shfl(bb, k >> 1) >> ((k & 1) << 4)) & 0xffff;
        short8 u = *(const short8*)(xb + (long)c * C_IN + l16 * 8);
#pragma unroll
        for (int j = 0; j < 8; j++) acc[j] += bf2f((unsigned short)u[j]);
        e += 4;
    }
    {
        int rem = deg - e;            // 0..3
        int k = e + g;
        unsigned int bv = __shfl(bb, k >> 1);   // shfl before divergence
        if (g < rem) {
            int c = (bv >> ((k & 1) << 4)) & 0xffff;
            short8 u = *(const short8*)(xb + (long)c * C_IN + l16 * 8);
#pragma unroll
            for (int j = 0; j < 8; j++) acc[j] += bf2f((unsigned short)u[j]);
        }
    }
#pragma unroll
    for (int j = 0; j < 8; j++) {
        acc[j] += __shfl_xor(acc[j], 16, 64);
        acc[j] += __shfl_xor(acc[j], 32, 64);
    }
    if (lane < 16) {
        float inv = 1.0f / fmaxf((float)degt, 1.0f);
        short8 mv;
#pragma unroll
        for (int j = 0; j < 8; j++) mv[j] = (short)f2bf(acc[j] * inv);
        *(short8*)(meanb + (long)n * C_IN + l16 * 8) = mv;
    }
}

// ---------------------------------------------------------------------------
// fused MLP (R4/R8-proven form, NO NT): out = relu(A@w1t^T+b1)@w2t^T+b2,
// A = [xb row | meanb row]. BM=32, 313 blocks, 256 thr. Phase 1 barrier-free
// (wave w owns h1 cols [w*128,+128)); ONE barrier; phase 2 from LDS h1.
// ---------------------------------------------------------------------------
__global__ __launch_bounds__(256)
void fused_mlp(const unsigned short* __restrict__ xb,     // [N][128] bf16
               const unsigned short* __restrict__ meanb,  // [N][128] bf16
               const unsigned short* __restrict__ w1t,    // [512][256] bf16
               const float* __restrict__ bias1,
               const unsigned short* __restrict__ w2t,    // [128][512] bf16
               const float* __restrict__ bias2,
               float* __restrict__ out, int M) {
    __shared__ __align__(16) unsigned short h1s[BM][520];

    const int t = threadIdx.x;
    const int m0 = blockIdx.x * BM;
    const int lane = t & 63;
    const int w = t >> 6;
    const int l16 = lane & 15;
    const int q = lane >> 4;        // 0..3
    const int q8 = q * 8;

    // A-fragments: k<128 from xb, k>=128 from meanb
    short8 a_reg[2][8];
#pragma unroll
    for (int mf = 0; mf < 2; mf++) {
        int gm = m0 + mf * 16 + l16;
        if (gm < M) {
            const unsigned short* ap = xb + (long)gm * C_IN + q8;
            const unsigned short* mp = meanb + (long)gm * C_IN + q8;
#pragma unroll
            for (int s = 0; s < 4; s++) {
                a_reg[mf][s]     = *(const short8*)(ap + s * 32);
                a_reg[mf][4 + s] = *(const short8*)(mp + s * 32);
            }
        } else {
#pragma unroll
            for (int s = 0; s < 8; s++) a_reg[mf][s] = short8{};
        }
    }

    // phase 1: wave w -> h1 cols [w*128, w*128+128), 4 chunks of 32
#pragma unroll
    for (int nc = 0; nc < 4; nc++) {
        const int colbase = w * 128 + nc * 32;
        f32x4 acc[2][2] = {};
#pragma unroll
        for (int s = 0; s < 8; s++) {
            short8 b0 = *(const short8*)(w1t + (long)(colbase + l16) * 256 + s * 32 + q8);
            short8 b1 = *(const short8*)(w1t + (long)(colbase + 16 + l16) * 256 + s * 32 + q8);
            acc[0][0] = __builtin_amdgcn_mfma_f32_16x16x32_bf16(a_reg[0][s], b0, acc[0][0], 0, 0, 0);
            acc[0][1] = __builtin_amdgcn_mfma_f32_16x16x32_bf16(a_reg[0][s], b1, acc[0][1], 0, 0, 0);
            acc[1][0] = __builtin_amdgcn_mfma_f32_16x16x32_bf16(a_reg[1][s], b0, acc[1][0], 0, 0, 0);
            acc[1][1] = __builtin_amdgcn_mfma_f32_16x16x32_bf16(a_reg[1][s], b1, acc[1][1], 0, 0, 0);
        }
        float bb0 = bias1[colbase + l16];
        float bb1 = bias1[colbase + 16 + l16];
#pragma unroll
        for (int mf = 0; mf < 2; mf++) {
#pragma unroll
            for (int r = 0; r < 4; r++) {
                int m = mf * 16 + q * 4 + r;
                h1s[m][colbase + l16]      = f2bf(fmaxf(acc[mf][0][r] + bb0, 0.f));
                h1s[m][colbase + 16 + l16] = f2bf(fmaxf(acc[mf][1][r] + bb1, 0.f));
            }
        }
    }
    __syncthreads();

    // phase 2: wave w -> out cols [w*32, w*32+32), 32 rows, K=512
    f32x4 acc2[2][2] = {};
    const int wn = w * 32;
#pragma unroll
    for (int ks = 0; ks < 16; ks++) {
        short8 a0 = *(const short8*)&h1s[l16][ks * 32 + q8];
        short8 a1 = *(const short8*)&h1s[16 + l16][ks * 32 + q8];
        short8 b0 = *(const short8*)(w2t + (long)(wn + l16) * H_DIM + ks * 32 + q8);
        short8 b1 = *(const short8*)(w2t + (long)(wn + 16 + l16) * H_DIM + ks * 32 + q8);
        acc2[0][0] = __builtin_amdgcn_mfma_f32_16x16x32_bf16(a0, b0, acc2[0][0], 0, 0, 0);
        acc2[0][1] = __builtin_amdgcn_mfma_f32_16x16x32_bf16(a0, b1, acc2[0][1], 0, 0, 0);
        acc2[1][0] = __builtin_amdgcn_mfma_f32_16x16x32_bf16(a1, b0, acc2[1][0], 0, 0, 0);
        acc2[1][1] = __builtin_amdgcn_mfma_f32_16x16x32_bf16(a1, b1, acc2[1][1], 0, 0, 0);
    }
#pragma unroll
    for (int mf = 0; mf < 2; mf++) {
#pragma unroll
        for (int nf = 0; nf < 2; nf++) {
            int gn = wn + nf * 16 + l16;
            float bb = bias2[gn];
#pragma unroll
            for (int r = 0; r < 4; r++) {
                int gm = m0 + mf * 16 + q * 4 + r;
                if (gm < M) out[(long)gm * O_DIM + gn] = acc2[mf][nf][r] + bb;
            }
        }
    }
}

extern "C" void kernel_launch(void* const* d_in, const int* in_sizes, int n_in,
                              void* d_out, int out_size, void* d_ws, size_t ws_size,
                              hipStream_t stream) {
    const float* x  = (const float*)d_in[0];   // [N, C]
    const int*   ei = (const int*)d_in[1];     // [2, E]
    const float* w1 = (const float*)d_in[2];   // [2C, H]
    const float* b1 = (const float*)d_in[3];   // [H]
    const float* w2 = (const float*)d_in[4];   // [H, O]
    const float* b2 = (const float*)d_in[5];   // [O]
    float* out = (float*)d_out;                // [N, O]

    const int N = in_sizes[0] / C_IN;
    const int E = in_sizes[1] / 2;

    // ws layout: xb [N][128] | meanb [N][128] | w1t [512][256] | w2t [128][512]
    //            | cnt_p [N*PAD] int | bucket [N*CAP] ushort
    unsigned short* xb = (unsigned short*)d_ws;
    unsigned short* meanb = xb + (size_t)N * C_IN;
    unsigned short* w1t = meanb + (size_t)N * C_IN;
    unsigned short* w2t = w1t + (size_t)H_DIM * (2 * C_IN);
    int* cnt_p = (int*)(w2t + (size_t)O_DIM * H_DIM);
    unsigned short* bucket = (unsigned short*)(cnt_p + (size_t)N * PAD);

    hipMemsetAsync(cnt_p, 0, (size_t)N * PAD * sizeof(int), stream);
    prep_fill<<<1024, 256, 0, stream>>>(w1, w1t, w2, w2t, x, xb, ei, cnt_p, bucket, N, E);
    gather_kernel<<<(N + 3) / 4, 256, 0, stream>>>(bucket, cnt_p, xb, meanb, N);
    fused_mlp<<<(N + BM - 1) / BM, 256, 0, stream>>>(xb, meanb, w1t, b1, w2t, b2, out, N);
}